// Round 1
// 863.911 us; speedup vs baseline: 1.3665x; 1.3665x over previous
//
#include <hip/hip_runtime.h>
#include <hip/hip_bf16.h>
#include <stdint.h>

// Problem constants
#define TOKENS 4096
#define DM     512
#define VOCAB  128000
#define BN     128                 // vocab rows per block (resident in LDS)
#define BM     512                 // token tile (8 waves x 64 tokens)
#define NCHUNK (VOCAB / BN)        // 1000
#define NTILE  (TOKENS / BM)       // 8

// ws layout (needs ~20.6 MB)
#define XBF_OFF  0
#define PART_OFF (TOKENS * DM * 2)                       // 4,194,304
#define T_OFF    (PART_OFF + NCHUNK * TOKENS * 4)        // +16,384,000
#define LDS_BYTES (BN * DM * 2)                          // 131072 (W only)

typedef __attribute__((ext_vector_type(8))) short short8;
typedef __attribute__((ext_vector_type(4))) float f32x4;

__device__ __forceinline__ unsigned short f2bf(float f) {
  unsigned u;
  __builtin_memcpy(&u, &f, 4);
  u += 0x7fffu + ((u >> 16) & 1u);        // round-to-nearest-even
  return (unsigned short)(u >> 16);
}

// ---------------- stage 0: x fp32 -> bf16, zero the output scalar ----------
__global__ void cvt_x_kernel(const float* __restrict__ x,
                             unsigned short* __restrict__ xb,
                             float* __restrict__ out) {
  int i = (blockIdx.x * 256 + threadIdx.x) * 4;   // 2048 blocks * 256 * 4 = 2,097,152
  float4 v = *(const float4*)(x + i);
  ushort4 o;
  o.x = f2bf(v.x); o.y = f2bf(v.y); o.z = f2bf(v.z); o.w = f2bf(v.w);
  *(ushort4*)(xb + i) = o;
  if (blockIdx.x == 0 && threadIdx.x == 0) out[0] = 0.0f;
}

// ---------------- stage 1: W-chunk-resident GEMM + per-chunk sumexp --------
// Block c: W rows [c*128, c*128+128) resident in LDS (bf16) in FRAGMENT-LINEAR
// layout [R:8][S:16][q:4][slot:16] (16B short8 units) where an A-fragment read
// for K-slice s is Wl[i*1024 + s*64 + (lane ^ (s&7))] -- a uniform-XOR
// permutation of 64 contiguous 16B slots (conflict-free read class).
// X (B-operand) fragments are loaded DIRECTLY from global (L2-resident bf16),
// double-buffered in registers. No barriers in the main loop. 8 waves, each
// owning all 128 vocab rows x 64 tokens (r=8, c=4 16x16 fragments).
__global__ __launch_bounds__(512, 2) void gemm_sumexp_kernel(
    const float* __restrict__ W, const unsigned short* __restrict__ Xb,
    float* __restrict__ part) {
  extern __shared__ char smem[];
  short8* Wl = (short8*)smem;                     // 8192 x 16B = 128 KB

  const int tid  = threadIdx.x;
  const int c    = blockIdx.x;
  const int lane = tid & 63;
  const int w    = tid >> 6;        // wave 0..7 -> token group
  const int ln   = lane & 15;
  const int quad = lane >> 4;

  // ---- load W chunk fp32 -> bf16 -> LDS (fragment-linear; once per block)
  {
    const float* Wg = W + (size_t)c * BN * DM;
    #pragma unroll
    for (int it = 0; it < 16; ++it) {
      int b  = it * 512 + tid;                // 0..8191 16B-blocks
      int n  = b >> 6;                        // W row 0..127
      int kb = b & 63;                        // 16B block within row (== lane)
      const f32x4* p = (const f32x4*)(Wg + n * DM + kb * 8);
      f32x4 v0 = __builtin_nontemporal_load(p);      // W is streamed: keep L2 for X
      f32x4 v1 = __builtin_nontemporal_load(p + 1);
      short8 s;
      s[0] = (short)f2bf(v0[0]); s[1] = (short)f2bf(v0[1]);
      s[2] = (short)f2bf(v0[2]); s[3] = (short)f2bf(v0[3]);
      s[4] = (short)f2bf(v1[0]); s[5] = (short)f2bf(v1[1]);
      s[6] = (short)f2bf(v1[2]); s[7] = (short)f2bf(v1[3]);
      int S = kb >> 2, q = kb & 3;
      Wl[(n >> 4) * 1024 + S * 64 + q * 16 + ((n & 15) ^ (S & 7))] = s;
    }
  }
  __syncthreads();                  // only barrier in the kernel

  #pragma unroll 1
  for (int t = 0; t < NTILE; ++t) {
    f32x4 acc[8][4];
    #pragma unroll
    for (int i = 0; i < 8; ++i)
      #pragma unroll
      for (int j = 0; j < 4; ++j)
        acc[i][j] = f32x4{0.f, 0.f, 0.f, 0.f};

    // B-fragment base: lane holds token (t*512 + w*64 + j*16 + ln),
    // k-elements quad*8..quad*8+7 within each K=32 slice s.
    const unsigned short* xrow =
        Xb + (size_t)(t * BM + w * 64 + ln) * DM + quad * 8;

    short8 bfA[4], bfB[4];
    #pragma unroll
    for (int j = 0; j < 4; ++j)
      bfA[j] = *(const short8*)(xrow + j * 16 * DM);           // s = 0

    #pragma unroll 1
    for (int sp = 0; sp < 8; ++sp) {
      const int s0 = 2 * sp, s1 = 2 * sp + 1;
      // prefetch odd slice into B buffer (hides L2 latency under MFMA)
      #pragma unroll
      for (int j = 0; j < 4; ++j)
        bfB[j] = *(const short8*)(xrow + j * 16 * DM + s1 * 32);
      {
        short8 af[8];
        const int rb = s0 * 64 + (lane ^ (s0 & 7));
        #pragma unroll
        for (int i = 0; i < 8; ++i) af[i] = Wl[i * 1024 + rb];
        __builtin_amdgcn_s_setprio(1);
        #pragma unroll
        for (int i = 0; i < 8; ++i)
          #pragma unroll
          for (int j = 0; j < 4; ++j)
            acc[i][j] = __builtin_amdgcn_mfma_f32_16x16x32_bf16(
                af[i], bfA[j], acc[i][j], 0, 0, 0);
        __builtin_amdgcn_s_setprio(0);
      }
      // prefetch next even slice (sp==7 reads a dead 64B past the tile; stays
      // inside ws, value never used -- branch-free steady state)
      #pragma unroll
      for (int j = 0; j < 4; ++j)
        bfA[j] = *(const short8*)(xrow + j * 16 * DM + (s0 + 2) * 32);
      {
        short8 af[8];
        const int rb = s1 * 64 + (lane ^ (s1 & 7));
        #pragma unroll
        for (int i = 0; i < 8; ++i) af[i] = Wl[i * 1024 + rb];
        __builtin_amdgcn_s_setprio(1);
        #pragma unroll
        for (int i = 0; i < 8; ++i)
          #pragma unroll
          for (int j = 0; j < 4; ++j)
            acc[i][j] = __builtin_amdgcn_mfma_f32_16x16x32_bf16(
                af[i], bfB[j], acc[i][j], 0, 0, 0);
        __builtin_amdgcn_s_setprio(0);
      }
    }

    // epilogue: acc[i][j][r] -> token = w*64 + j*16 + ln (col = lane&15),
    // vocab row = i*16 + quad*4 + r. Each wave owns its 64 tokens across ALL
    // 128 rows: sum exp per lane, fold quads with two shfl_xor, store direct.
    #pragma unroll
    for (int j = 0; j < 4; ++j) {
      float e = 0.f;
      #pragma unroll
      for (int i = 0; i < 8; ++i) {
        #pragma unroll
        for (int r = 0; r < 4; ++r) e += __expf(acc[i][j][r]);
      }
      e += __shfl_xor(e, 16, 64);
      e += __shfl_xor(e, 32, 64);
      if (lane < 16) {
        float* pp = part + (size_t)c * TOKENS + t * BM + w * 64 + j * 16 + lane;
        __builtin_nontemporal_store(e, pp);    // part is write-once/read-once
      }
    }
  }
}

// ---------------- stage 2a: exact fp32 target scores -----------------------
__global__ void target_dot_kernel(const float* __restrict__ x,
                                  const float* __restrict__ W,
                                  const int* __restrict__ tgt,
                                  float* __restrict__ T) {
  int wave = threadIdx.x >> 6, lane = threadIdx.x & 63;
  int i = blockIdx.x * 4 + wave;                 // 1024 blocks * 4 waves = 4096
  int r = tgt[i];
  const float4* xp = (const float4*)(x + (size_t)i * DM + lane * 8);
  const float4* wp = (const float4*)(W + (size_t)r * DM + lane * 8);
  float4 a0 = xp[0], a1 = xp[1], b0 = wp[0], b1 = wp[1];
  float s = a0.x * b0.x + a0.y * b0.y + a0.z * b0.z + a0.w * b0.w
          + a1.x * b1.x + a1.y * b1.y + a1.z * b1.z + a1.w * b1.w;
  #pragma unroll
  for (int m = 32; m >= 1; m >>= 1) s += __shfl_xor(s, m, 64);
  if (lane == 0) T[i] = s;
}

// ---------------- stage 2b: reduce chunks, loss, total ---------------------
__global__ void reduce_loss_kernel(const float* __restrict__ part,
                                   const float* __restrict__ T,
                                   float* __restrict__ out) {
  __shared__ float red[256];
  int tid = threadIdx.x;
  int tok = blockIdx.x * 64 + (tid & 63);        // 64 blocks * 64 tokens
  int g = tid >> 6;
  float S = 0.f;
  #pragma unroll 5
  for (int cc = g; cc < NCHUNK; cc += 4) S += part[cc * TOKENS + tok];
  red[tid] = S;
  __syncthreads();
  if (tid < 64) {
    float Sa = red[tid] + red[64 + tid] + red[128 + tid] + red[192 + tid];
    float loss = __logf(Sa) - T[tok];            // = log s - t (max-free form)
    #pragma unroll
    for (int m = 32; m >= 1; m >>= 1) loss += __shfl_xor(loss, m, 64);
    if (tid == 0) atomicAdd(out, loss);
  }
}

extern "C" void kernel_launch(void* const* d_in, const int* in_sizes, int n_in,
                              void* d_out, int out_size, void* d_ws, size_t ws_size,
                              hipStream_t stream) {
  const float* x   = (const float*)d_in[0];
  const float* W   = (const float*)d_in[1];
  const int*   tgt = (const int*)d_in[2];
  float* out = (float*)d_out;

  unsigned short* xb   = (unsigned short*)((char*)d_ws + XBF_OFF);
  float*          part = (float*)((char*)d_ws + PART_OFF);
  float*          T    = (float*)((char*)d_ws + T_OFF);

  // allow 128 KB dynamic LDS (idempotent; host-side, safe under graph capture)
  hipFuncSetAttribute(reinterpret_cast<const void*>(gemm_sumexp_kernel),
                      hipFuncAttributeMaxDynamicSharedMemorySize, LDS_BYTES);

  cvt_x_kernel<<<TOKENS * DM / (256 * 4), 256, 0, stream>>>(x, xb, out);
  gemm_sumexp_kernel<<<NCHUNK, 512, LDS_BYTES, stream>>>(W, xb, part);
  target_dot_kernel<<<TOKENS / 4, 256, 0, stream>>>(x, W, tgt, T);
  reduce_loss_kernel<<<TOKENS / 64, 256, 0, stream>>>(part, T, out);
}